// Round 1
// baseline (1700.279 us; speedup 1.0000x reference)
//
#include <hip/hip_runtime.h>
#include <math.h>

// ---------------------------------------------------------------------------
// Santacoder MQA prefill: B=2, S=1024, D=2048, H=16, HD=128, L=2, FF=8192
// Strategy: bf16 MFMA for all matmuls (threshold 1.06e-1 admits bf16),
// weights converted+transposed to bf16 once per call, m97-style GEMM
// (128x128 tile, BK=32, global_load_lds w16), flash attention with online
// softmax, f32 residual stream.
// ---------------------------------------------------------------------------

typedef __bf16 bf16x8 __attribute__((ext_vector_type(8)));
typedef __bf16 bf16x4v __attribute__((ext_vector_type(4)));
typedef float floatx4 __attribute__((ext_vector_type(4)));

typedef const __attribute__((address_space(1))) void* gas_ptr;
typedef __attribute__((address_space(3))) void* las_ptr;

__device__ __forceinline__ void glds16(const __bf16* g, __bf16* l) {
  __builtin_amdgcn_global_load_lds((gas_ptr)g, (las_ptr)l, 16, 0, 0);
}

__device__ __forceinline__ float gelu_tanh(float x) {
  float u = 0.7978845608028654f * (x + 0.044715f * x * x * x);
  return 0.5f * x * (1.f + tanhf(u));
}

// ---------------------------------------------------------------------------
// Embedding: h[t] = wte[ids[t]] + wpe[pos[t]]
// ---------------------------------------------------------------------------
__global__ __launch_bounds__(256)
void embed_kernel(const int* __restrict__ ids, const int* __restrict__ pos,
                  const float* __restrict__ wte, const float* __restrict__ wpe,
                  float* __restrict__ out)
{
  const int t = blockIdx.x;
  const int id = ids[t], pp = pos[t];
  const float4* a = (const float4*)(wte + (size_t)id * 2048);
  const float4* b = (const float4*)(wpe + (size_t)pp * 2048);
  float4* o = (float4*)(out + (size_t)t * 2048);
#pragma unroll
  for (int j = 0; j < 2; j++) {
    int i = threadIdx.x + j * 256;
    float4 x = a[i], y = b[i];
    x.x += y.x; x.y += y.y; x.z += y.z; x.w += y.w;
    o[i] = x;
  }
}

// ---------------------------------------------------------------------------
// Weight convert + transpose: in f32 [K][N] -> out bf16 [N][K]; grid.z = layer
// ---------------------------------------------------------------------------
__global__ __launch_bounds__(256)
void wcvt_kernel(const float* __restrict__ in, __bf16* __restrict__ out,
                 const int K, const int N)
{
  __shared__ __bf16 tile[32][36];
  const size_t msz = (size_t)K * N;
  in  += (size_t)blockIdx.z * msz;
  out += (size_t)blockIdx.z * msz;
  const int n0 = blockIdx.x * 32, k0 = blockIdx.y * 32;
  const int t = threadIdx.x;
  const int r = t >> 3, c = (t & 7) * 4;
  const float4 v = *(const float4*)&in[(size_t)(k0 + r) * N + n0 + c];
  tile[r][c + 0] = (__bf16)v.x;
  tile[r][c + 1] = (__bf16)v.y;
  tile[r][c + 2] = (__bf16)v.z;
  tile[r][c + 3] = (__bf16)v.w;
  __syncthreads();
  bf16x4v w;
  w.x = tile[c + 0][r]; w.y = tile[c + 1][r];
  w.z = tile[c + 2][r]; w.w = tile[c + 3][r];
  *(bf16x4v*)&out[(size_t)(n0 + r) * K + k0 + c] = w;
}

// ---------------------------------------------------------------------------
// V transpose: qkv[:, 2176:2304] bf16 -> vT [B][128][1024]
// ---------------------------------------------------------------------------
__global__ __launch_bounds__(256)
void vtr_kernel(const __bf16* __restrict__ qkvb, __bf16* __restrict__ vT)
{
  __shared__ __bf16 tile[32][36];
  const int d0 = blockIdx.x * 32, s0 = blockIdx.y * 32, b = blockIdx.z;
  const int t = threadIdx.x;
  const int r = t >> 3, c = (t & 7) * 4;
  bf16x4v v = *(const bf16x4v*)&qkvb[(size_t)(b * 1024 + s0 + r) * 2304 + 2176 + d0 + c];
  tile[r][c + 0] = v.x; tile[r][c + 1] = v.y;
  tile[r][c + 2] = v.z; tile[r][c + 3] = v.w;
  __syncthreads();
  bf16x4v w;
  w.x = tile[c + 0][r]; w.y = tile[c + 1][r];
  w.z = tile[c + 2][r]; w.w = tile[c + 3][r];
  *(bf16x4v*)&vT[(size_t)b * 131072 + (size_t)(d0 + r) * 1024 + s0 + c] = w;
}

// ---------------------------------------------------------------------------
// Fused (optional residual-add) + LayerNorm. One block per row of 2048.
// in1 (+in2) -> res_out (opt), normalized -> out_b (bf16, opt) / out_f (opt)
// ---------------------------------------------------------------------------
__global__ __launch_bounds__(256)
void ln_kernel(const float* __restrict__ in1, const float* __restrict__ in2,
               float* __restrict__ res_out, __bf16* __restrict__ out_b,
               float* __restrict__ out_f,
               const float* __restrict__ gw, const float* __restrict__ gb)
{
  const int row = blockIdx.x;
  const int tid = threadIdx.x;
  const size_t base = (size_t)row * 2048;
  float4 v[2];
  float s = 0.f, sq = 0.f;
#pragma unroll
  for (int j = 0; j < 2; j++) {
    const int idx = tid + j * 256;
    float4 a = ((const float4*)(in1 + base))[idx];
    if (in2) {
      float4 bb = ((const float4*)(in2 + base))[idx];
      a.x += bb.x; a.y += bb.y; a.z += bb.z; a.w += bb.w;
    }
    if (res_out) ((float4*)(res_out + base))[idx] = a;
    v[j] = a;
    s  += a.x + a.y + a.z + a.w;
    sq += a.x * a.x + a.y * a.y + a.z * a.z + a.w * a.w;
  }
  __shared__ float rs[4], rq[4];
  __shared__ float sh_stats[2];
#pragma unroll
  for (int off = 32; off > 0; off >>= 1) {
    s  += __shfl_down(s, off);
    sq += __shfl_down(sq, off);
  }
  const int lane = tid & 63, wave = tid >> 6;
  if (lane == 0) { rs[wave] = s; rq[wave] = sq; }
  __syncthreads();
  if (tid == 0) {
    float S = rs[0] + rs[1] + rs[2] + rs[3];
    float Q = rq[0] + rq[1] + rq[2] + rq[3];
    float mean = S * (1.f / 2048.f);
    float var  = Q * (1.f / 2048.f) - mean * mean;
    sh_stats[0] = mean;
    sh_stats[1] = rsqrtf(var + 1e-5f);
  }
  __syncthreads();
  const float mean = sh_stats[0], rstd = sh_stats[1];
#pragma unroll
  for (int j = 0; j < 2; j++) {
    const int idx = tid + j * 256;
    float4 a = v[j];
    float4 g4 = ((const float4*)gw)[idx];
    float4 b4 = ((const float4*)gb)[idx];
    float y0 = (a.x - mean) * rstd * g4.x + b4.x;
    float y1 = (a.y - mean) * rstd * g4.y + b4.y;
    float y2 = (a.z - mean) * rstd * g4.z + b4.z;
    float y3 = (a.w - mean) * rstd * g4.w + b4.w;
    if (out_b) {
      bf16x4v w;
      w.x = (__bf16)y0; w.y = (__bf16)y1; w.z = (__bf16)y2; w.w = (__bf16)y3;
      *(bf16x4v*)&out_b[base + (size_t)idx * 4] = w;
    }
    if (out_f) {
      float4 w; w.x = y0; w.y = y1; w.z = y2; w.w = y3;
      ((float4*)(out_f + base))[idx] = w;
    }
  }
}

// ---------------------------------------------------------------------------
// GEMM: C[M][N] = A[M][K] * Bt[N][K]^T + bias.  m97 structure:
// 128x128 tile, BK=32, 4 waves each 64x64 (4x4 of 16x16x32 bf16 MFMA),
// staging via global_load_lds width 16.
// MODE 0: f32 out + bias; 1: bf16 out + bias; 2: bf16 out + bias + gelu
// ---------------------------------------------------------------------------
template<int MODE>
__global__ __launch_bounds__(256)
void gemm_bt_kernel(const __bf16* __restrict__ A, const __bf16* __restrict__ Bt,
                    const float* __restrict__ bias, void* __restrict__ Cout,
                    const int M, const int N, const int K)
{
  __shared__ __bf16 As[128 * 32];
  __shared__ __bf16 Bs[128 * 32];
  const int tid  = threadIdx.x;
  const int lane = tid & 63;
  const int wave = tid >> 6;
  const int col  = lane & 15;
  const int quad = lane >> 4;
  const int m0 = blockIdx.y * 128;
  const int n0 = blockIdx.x * 128;
  const int wm = (wave & 1) * 64;
  const int wn = (wave >> 1) * 64;
  floatx4 acc[4][4] = {};

  const int srow = tid >> 2;
  const int scol = (tid & 3) * 8;
  const __bf16* Ag = A  + (size_t)(m0 + srow) * K + scol;
  const __bf16* Bg = Bt + (size_t)(n0 + srow) * K + scol;
  const size_t rowskip = (size_t)64 * K;

  for (int k0 = 0; k0 < K; k0 += 32) {
    glds16(Ag + k0,           As + tid * 8);
    glds16(Ag + k0 + rowskip, As + 2048 + tid * 8);
    glds16(Bg + k0,           Bs + tid * 8);
    glds16(Bg + k0 + rowskip, Bs + 2048 + tid * 8);
    __syncthreads();
    bf16x8 af[4], bf[4];
#pragma unroll
    for (int mi = 0; mi < 4; mi++)
      af[mi] = *(const bf16x8*)&As[(wm + mi * 16 + col) * 32 + quad * 8];
#pragma unroll
    for (int ni = 0; ni < 4; ni++)
      bf[ni] = *(const bf16x8*)&Bs[(wn + ni * 16 + col) * 32 + quad * 8];
#pragma unroll
    for (int mi = 0; mi < 4; mi++)
#pragma unroll
      for (int ni = 0; ni < 4; ni++)
        acc[mi][ni] = __builtin_amdgcn_mfma_f32_16x16x32_bf16(af[mi], bf[ni], acc[mi][ni], 0, 0, 0);
    __syncthreads();
  }

#pragma unroll
  for (int ni = 0; ni < 4; ni++) {
    const int cc = n0 + wn + ni * 16 + col;
    const float bv = bias[cc];
#pragma unroll
    for (int mi = 0; mi < 4; mi++) {
#pragma unroll
      for (int r = 0; r < 4; r++) {
        const int rr = m0 + wm + mi * 16 + quad * 4 + r;
        float v = acc[mi][ni][r] + bv;
        if constexpr (MODE == 2) v = gelu_tanh(v);
        if constexpr (MODE == 0)
          ((float*)Cout)[(size_t)rr * N + cc] = v;
        else
          ((__bf16*)Cout)[(size_t)rr * N + cc] = (__bf16)v;
      }
    }
  }
}

// ---------------------------------------------------------------------------
// Flash attention (MQA): grid (S/64, H, B), 256 threads (4 waves).
// Each wave owns 16 query rows; k-tiles of 64 keys; online softmax.
// ---------------------------------------------------------------------------
__global__ __launch_bounds__(256)
void flash_kernel(const __bf16* __restrict__ qkv, const __bf16* __restrict__ vT,
                  __bf16* __restrict__ ctx)
{
  const int qt = blockIdx.x, h = blockIdx.y, b = blockIdx.z;
  const int tid  = threadIdx.x;
  const int lane = tid & 63, wave = tid >> 6;
  const int col  = lane & 15, quad = lane >> 4;
  __shared__ __bf16 Qs[64 * 128];
  __shared__ __bf16 Ks[64 * 128];
  __shared__ __bf16 Vs[128 * 64];   // transposed: [d][key]
  __shared__ __bf16 Ps[4][16 * 64];

  // stage Q tile (64 q rows x 128)
#pragma unroll
  for (int p = 0; p < 4; p++) {
    int c = tid + p * 256;
    glds16(qkv + (size_t)(b * 1024 + qt * 64 + (c >> 4)) * 2304 + h * 128 + (c & 15) * 8,
           Qs + c * 8);
  }

  float m_i[4], l_i[4];
  floatx4 o[8] = {};
#pragma unroll
  for (int r = 0; r < 4; r++) { m_i[r] = -1e30f; l_i[r] = 0.f; }

  for (int kt = 0; kt <= qt; kt++) {
    __syncthreads();
#pragma unroll
    for (int p = 0; p < 4; p++) {
      int c = tid + p * 256;
      glds16(qkv + (size_t)(b * 1024 + kt * 64 + (c >> 4)) * 2304 + 2048 + (c & 15) * 8,
             Ks + c * 8);
    }
#pragma unroll
    for (int p = 0; p < 4; p++) {
      int c = tid + p * 256;
      glds16(vT + (size_t)b * 131072 + (size_t)(c >> 3) * 1024 + kt * 64 + (c & 7) * 8,
             Vs + c * 8);
    }
    __syncthreads();

    // scores: 16 q rows x 64 keys per wave
    floatx4 sc[4] = {};
#pragma unroll
    for (int kk = 0; kk < 4; kk++) {
      bf16x8 qa = *(const bf16x8*)&Qs[(wave * 16 + col) * 128 + kk * 32 + quad * 8];
#pragma unroll
      for (int ni = 0; ni < 4; ni++) {
        bf16x8 kb = *(const bf16x8*)&Ks[(ni * 16 + col) * 128 + kk * 32 + quad * 8];
        sc[ni] = __builtin_amdgcn_mfma_f32_16x16x32_bf16(qa, kb, sc[ni], 0, 0, 0);
      }
    }

    const bool diag = (kt == qt);
#pragma unroll
    for (int r = 0; r < 4; r++) {
      const int rowL = wave * 16 + quad * 4 + r;
      float mx = -1e30f;
#pragma unroll
      for (int ni = 0; ni < 4; ni++) {
        float s = sc[ni][r] * 0.08838834764831845f;
        if (diag && (ni * 16 + col) > rowL) s = -1e30f;
        sc[ni][r] = s;
        mx = fmaxf(mx, s);
      }
#pragma unroll
      for (int off = 1; off < 16; off <<= 1) mx = fmaxf(mx, __shfl_xor(mx, off));
      const float mnew = fmaxf(m_i[r], mx);
      const float alpha = __expf(m_i[r] - mnew);
      l_i[r] *= alpha;
      float rsum = 0.f;
#pragma unroll
      for (int ni = 0; ni < 4; ni++) {
        float p = __expf(sc[ni][r] - mnew);
        sc[ni][r] = p;
        rsum += p;
      }
#pragma unroll
      for (int off = 1; off < 16; off <<= 1) rsum += __shfl_xor(rsum, off);
      l_i[r] += rsum;
      m_i[r] = mnew;
#pragma unroll
      for (int nd = 0; nd < 8; nd++) o[nd][r] *= alpha;
    }

    // P (C-layout) -> LDS -> A-operand layout
    __bf16* Pw = &Ps[wave][0];
#pragma unroll
    for (int r = 0; r < 4; r++)
#pragma unroll
      for (int ni = 0; ni < 4; ni++)
        Pw[(quad * 4 + r) * 64 + ni * 16 + col] = (__bf16)sc[ni][r];

#pragma unroll
    for (int kk = 0; kk < 2; kk++) {
      bf16x8 pa = *(const bf16x8*)&Pw[col * 64 + kk * 32 + quad * 8];
#pragma unroll
      for (int nd = 0; nd < 8; nd++) {
        bf16x8 vb = *(const bf16x8*)&Vs[(nd * 16 + col) * 64 + kk * 32 + quad * 8];
        o[nd] = __builtin_amdgcn_mfma_f32_16x16x32_bf16(pa, vb, o[nd], 0, 0, 0);
      }
    }
  }

#pragma unroll
  for (int r = 0; r < 4; r++) {
    const float inv = 1.f / l_i[r];
    const int row = qt * 64 + wave * 16 + quad * 4 + r;
    const size_t base = (size_t)(b * 1024 + row) * 2048 + h * 128;
#pragma unroll
    for (int nd = 0; nd < 8; nd++)
      ctx[base + nd * 16 + col] = (__bf16)(o[nd][r] * inv);
  }
}

// ---------------------------------------------------------------------------
// Orchestration
// ---------------------------------------------------------------------------
extern "C" void kernel_launch(void* const* d_in, const int* in_sizes, int n_in,
                              void* d_out, int out_size, void* d_ws, size_t ws_size,
                              hipStream_t stream)
{
  (void)in_sizes; (void)n_in; (void)out_size; (void)ws_size;
  const int*   ids = (const int*)d_in[0];
  const int*   pos = (const int*)d_in[1];
  const float* wte = (const float*)d_in[2];
  const float* wpe = (const float*)d_in[3];
  const float* caw = (const float*)d_in[4];
  const float* cab = (const float*)d_in[5];
  const float* cpw = (const float*)d_in[6];
  const float* cpb = (const float*)d_in[7];
  const float* l1w = (const float*)d_in[8];
  const float* l1b = (const float*)d_in[9];
  const float* l2w = (const float*)d_in[10];
  const float* l2b = (const float*)d_in[11];
  const float* fcw = (const float*)d_in[12];
  const float* fcb = (const float*)d_in[13];
  const float* mpw = (const float*)d_in[14];
  const float* mpb = (const float*)d_in[15];
  const float* lfw = (const float*)d_in[16];
  const float* lfb = (const float*)d_in[17];
  float* out = (float*)d_out;

  char* ws = (char*)d_ws;
  float*  resA  = (float*)(ws + 0);          // res stream            16.8MB
  float*  resB  = (float*)(ws + 16777216);   // res2 stream           16.8MB
  float*  hbuf  = (float*)(ws + 33554432);   // attn_out / mlp f32    16.8MB
  __bf16* xb    = (__bf16*)(ws + 50331648);  // LN out bf16            8.4MB
  __bf16* qkvb  = (__bf16*)(ws + 58720256);  // qkv bf16               9.4MB
  __bf16* ctxb  = (__bf16*)(ws + 68157440);  // attn ctx bf16          8.4MB
  __bf16* mlp1b = (__bf16*)(ws + 76546048);  // gelu(fc) bf16         33.6MB
  __bf16* vtb   = (__bf16*)(ws + 110100480); // V^T [B][128][1024]     0.5MB
  __bf16* wqkvT = (__bf16*)(ws + 110624768); // [L][2304][2048]       18.9MB
  __bf16* wprjT = (__bf16*)(ws + 129499136); // [L][2048][2048]       16.8MB
  __bf16* wfcT  = (__bf16*)(ws + 146276352); // [L][8192][2048]       67.1MB
  __bf16* wmpT  = (__bf16*)(ws + 213385216); // [L][2048][8192]       67.1MB

  // weight conversion (every call — inputs are restored before each launch)
  wcvt_kernel<<<dim3(72, 64, 2),  256, 0, stream>>>(caw, wqkvT, 2048, 2304);
  wcvt_kernel<<<dim3(64, 64, 2),  256, 0, stream>>>(cpw, wprjT, 2048, 2048);
  wcvt_kernel<<<dim3(256, 64, 2), 256, 0, stream>>>(fcw, wfcT, 2048, 8192);
  wcvt_kernel<<<dim3(64, 256, 2), 256, 0, stream>>>(mpw, wmpT, 8192, 2048);

  embed_kernel<<<2048, 256, 0, stream>>>(ids, pos, wte, wpe, resA);

  for (int l = 0; l < 2; l++) {
    if (l == 0)
      ln_kernel<<<2048, 256, 0, stream>>>(resA, (const float*)nullptr,
                                          (float*)nullptr, xb, (float*)nullptr,
                                          l1w, l1b);
    else
      ln_kernel<<<2048, 256, 0, stream>>>(hbuf, resB, resA, xb, (float*)nullptr,
                                          l1w + 2048, l1b + 2048);

    gemm_bt_kernel<1><<<dim3(18, 16), 256, 0, stream>>>(
        xb, wqkvT + (size_t)l * 2304 * 2048, cab + l * 2304, qkvb, 2048, 2304, 2048);

    vtr_kernel<<<dim3(4, 32, 2), 256, 0, stream>>>(qkvb, vtb);
    flash_kernel<<<dim3(16, 16, 2), 256, 0, stream>>>(qkvb, vtb, ctxb);

    gemm_bt_kernel<0><<<dim3(16, 16), 256, 0, stream>>>(
        ctxb, wprjT + (size_t)l * 2048 * 2048, cpb + l * 2048, hbuf, 2048, 2048, 2048);

    ln_kernel<<<2048, 256, 0, stream>>>(hbuf, resA, resB, xb, (float*)nullptr,
                                        l2w + l * 2048, l2b + l * 2048);

    gemm_bt_kernel<2><<<dim3(64, 16), 256, 0, stream>>>(
        xb, wfcT + (size_t)l * 8192 * 2048, fcb + l * 8192, mlp1b, 2048, 8192, 2048);

    gemm_bt_kernel<0><<<dim3(16, 16), 256, 0, stream>>>(
        mlp1b, wmpT + (size_t)l * 2048 * 8192, mpb + l * 2048, hbuf, 2048, 2048, 8192);
  }

  ln_kernel<<<2048, 256, 0, stream>>>(hbuf, resB, (float*)nullptr,
                                      (__bf16*)nullptr, out, lfw, lfb);
}

// Round 2
// 1427.709 us; speedup vs baseline: 1.1909x; 1.1909x over previous
//
#include <hip/hip_runtime.h>
#include <math.h>

// ---------------------------------------------------------------------------
// Santacoder MQA prefill: B=2, S=1024, D=2048, H=16, HD=128, L=2, FF=8192
// R2: split-K GEMMs (mp x4, proj x2, qkv x2) to fix 1-block/CU occupancy
// (R1: mp at 223us, Occupancy 11%, MfmaUtil 12%). Reductions fused into LN.
// Weights converted JIT per layer (ws budget) into single-layer buffers.
// ---------------------------------------------------------------------------

typedef __bf16 bf16x8 __attribute__((ext_vector_type(8)));
typedef __bf16 bf16x4v __attribute__((ext_vector_type(4)));
typedef float floatx4 __attribute__((ext_vector_type(4)));

typedef const __attribute__((address_space(1))) void* gas_ptr;
typedef __attribute__((address_space(3))) void* las_ptr;

__device__ __forceinline__ void glds16(const __bf16* g, __bf16* l) {
  __builtin_amdgcn_global_load_lds((gas_ptr)g, (las_ptr)l, 16, 0, 0);
}

__device__ __forceinline__ float gelu_tanh(float x) {
  float u = 0.7978845608028654f * (x + 0.044715f * x * x * x);
  return 0.5f * x * (1.f + tanhf(u));
}

// ---------------------------------------------------------------------------
// Embedding: h[t] = wte[ids[t]] + wpe[pos[t]]
// ---------------------------------------------------------------------------
__global__ __launch_bounds__(256)
void embed_kernel(const int* __restrict__ ids, const int* __restrict__ pos,
                  const float* __restrict__ wte, const float* __restrict__ wpe,
                  float* __restrict__ out)
{
  const int t = blockIdx.x;
  const int id = ids[t], pp = pos[t];
  const float4* a = (const float4*)(wte + (size_t)id * 2048);
  const float4* b = (const float4*)(wpe + (size_t)pp * 2048);
  float4* o = (float4*)(out + (size_t)t * 2048);
#pragma unroll
  for (int j = 0; j < 2; j++) {
    int i = threadIdx.x + j * 256;
    float4 x = a[i], y = b[i];
    x.x += y.x; x.y += y.y; x.z += y.z; x.w += y.w;
    o[i] = x;
  }
}

// ---------------------------------------------------------------------------
// Weight convert + transpose: in f32 [K][N] -> out bf16 [N][K]
// ---------------------------------------------------------------------------
__global__ __launch_bounds__(256)
void wcvt_kernel(const float* __restrict__ in, __bf16* __restrict__ out,
                 const int K, const int N)
{
  __shared__ __bf16 tile[32][36];
  const int n0 = blockIdx.x * 32, k0 = blockIdx.y * 32;
  const int t = threadIdx.x;
  const int r = t >> 3, c = (t & 7) * 4;
  const float4 v = *(const float4*)&in[(size_t)(k0 + r) * N + n0 + c];
  tile[r][c + 0] = (__bf16)v.x;
  tile[r][c + 1] = (__bf16)v.y;
  tile[r][c + 2] = (__bf16)v.z;
  tile[r][c + 3] = (__bf16)v.w;
  __syncthreads();
  bf16x4v w;
  w.x = tile[c + 0][r]; w.y = tile[c + 1][r];
  w.z = tile[c + 2][r]; w.w = tile[c + 3][r];
  *(bf16x4v*)&out[(size_t)(n0 + r) * K + k0 + c] = w;
}

// ---------------------------------------------------------------------------
// V transpose: qkv[:, 2176:2304] bf16 -> vT [B][128][1024]
// ---------------------------------------------------------------------------
__global__ __launch_bounds__(256)
void vtr_kernel(const __bf16* __restrict__ qkvb, __bf16* __restrict__ vT)
{
  __shared__ __bf16 tile[32][36];
  const int d0 = blockIdx.x * 32, s0 = blockIdx.y * 32, b = blockIdx.z;
  const int t = threadIdx.x;
  const int r = t >> 3, c = (t & 7) * 4;
  bf16x4v v = *(const bf16x4v*)&qkvb[(size_t)(b * 1024 + s0 + r) * 2304 + 2176 + d0 + c];
  tile[r][c + 0] = v.x; tile[r][c + 1] = v.y;
  tile[r][c + 2] = v.z; tile[r][c + 3] = v.w;
  __syncthreads();
  bf16x4v w;
  w.x = tile[c + 0][r]; w.y = tile[c + 1][r];
  w.z = tile[c + 2][r]; w.w = tile[c + 3][r];
  *(bf16x4v*)&vT[(size_t)b * 131072 + (size_t)(d0 + r) * 1024 + s0 + c] = w;
}

// ---------------------------------------------------------------------------
// Fused partial-sum reduce + bias + residual-add + LayerNorm.
// x = p0 [+p1 +p2 +p3] [+cbias] [+resid]; res_out=x (opt); LN(x) -> out_b/out_f
// ---------------------------------------------------------------------------
__global__ __launch_bounds__(256)
void ln_red_kernel(const float* __restrict__ p0, const float* __restrict__ p1,
                   const float* __restrict__ p2, const float* __restrict__ p3,
                   const float* __restrict__ cbias, const float* __restrict__ resid,
                   float* __restrict__ res_out, __bf16* __restrict__ out_b,
                   float* __restrict__ out_f,
                   const float* __restrict__ gw, const float* __restrict__ gb)
{
  const int row = blockIdx.x;
  const int tid = threadIdx.x;
  const size_t base = (size_t)row * 2048;
  float4 v[2];
  float s = 0.f, sq = 0.f;
#pragma unroll
  for (int j = 0; j < 2; j++) {
    const int idx = tid + j * 256;
    float4 a = ((const float4*)(p0 + base))[idx];
    if (p1) { float4 t = ((const float4*)(p1 + base))[idx];
      a.x += t.x; a.y += t.y; a.z += t.z; a.w += t.w; }
    if (p2) { float4 t = ((const float4*)(p2 + base))[idx];
      a.x += t.x; a.y += t.y; a.z += t.z; a.w += t.w; }
    if (p3) { float4 t = ((const float4*)(p3 + base))[idx];
      a.x += t.x; a.y += t.y; a.z += t.z; a.w += t.w; }
    if (cbias) { float4 t = ((const float4*)cbias)[idx];
      a.x += t.x; a.y += t.y; a.z += t.z; a.w += t.w; }
    if (resid) { float4 t = ((const float4*)(resid + base))[idx];
      a.x += t.x; a.y += t.y; a.z += t.z; a.w += t.w; }
    if (res_out) ((float4*)(res_out + base))[idx] = a;
    v[j] = a;
    s  += a.x + a.y + a.z + a.w;
    sq += a.x * a.x + a.y * a.y + a.z * a.z + a.w * a.w;
  }
  __shared__ float rs[4], rq[4];
  __shared__ float sh_stats[2];
#pragma unroll
  for (int off = 32; off > 0; off >>= 1) {
    s  += __shfl_down(s, off);
    sq += __shfl_down(sq, off);
  }
  const int lane = tid & 63, wave = tid >> 6;
  if (lane == 0) { rs[wave] = s; rq[wave] = sq; }
  __syncthreads();
  if (tid == 0) {
    float S = rs[0] + rs[1] + rs[2] + rs[3];
    float Q = rq[0] + rq[1] + rq[2] + rq[3];
    float mean = S * (1.f / 2048.f);
    float var  = Q * (1.f / 2048.f) - mean * mean;
    sh_stats[0] = mean;
    sh_stats[1] = rsqrtf(var + 1e-5f);
  }
  __syncthreads();
  const float mean = sh_stats[0], rstd = sh_stats[1];
#pragma unroll
  for (int j = 0; j < 2; j++) {
    const int idx = tid + j * 256;
    float4 a = v[j];
    float4 g4 = ((const float4*)gw)[idx];
    float4 b4 = ((const float4*)gb)[idx];
    float y0 = (a.x - mean) * rstd * g4.x + b4.x;
    float y1 = (a.y - mean) * rstd * g4.y + b4.y;
    float y2 = (a.z - mean) * rstd * g4.z + b4.z;
    float y3 = (a.w - mean) * rstd * g4.w + b4.w;
    if (out_b) {
      bf16x4v w;
      w.x = (__bf16)y0; w.y = (__bf16)y1; w.z = (__bf16)y2; w.w = (__bf16)y3;
      *(bf16x4v*)&out_b[base + (size_t)idx * 4] = w;
    }
    if (out_f) {
      float4 w; w.x = y0; w.y = y1; w.z = y2; w.w = y3;
      ((float4*)(out_f + base))[idx] = w;
    }
  }
}

// ---------------------------------------------------------------------------
// qkv split-K reduce: out_bf16 = p0 + p1 + bias   (N = 2304)
// ---------------------------------------------------------------------------
__global__ __launch_bounds__(256)
void bias_red_bf16_kernel(const float* __restrict__ p0, const float* __restrict__ p1,
                          const float* __restrict__ bias, __bf16* __restrict__ out)
{
  const size_t i = ((size_t)blockIdx.x * 256 + threadIdx.x) * 4;
  const int col = (int)(i % 2304);
  float4 a = *(const float4*)(p0 + i);
  const float4 b = *(const float4*)(p1 + i);
  const float4 c = *(const float4*)(bias + col);
  bf16x4v w;
  w.x = (__bf16)(a.x + b.x + c.x);
  w.y = (__bf16)(a.y + b.y + c.y);
  w.z = (__bf16)(a.z + b.z + c.z);
  w.w = (__bf16)(a.w + b.w + c.w);
  *(bf16x4v*)(out + i) = w;
}

// ---------------------------------------------------------------------------
// GEMM: C = A[M][K] * Bt[N][K]^T (+bias). 128x128 tile, BK=32, 4 waves,
// global_load_lds w16. Row stride is full K; blockIdx.z selects a K-split of
// length Kper. MODE 0: f32+bias; 1: bf16+bias; 2: bf16+bias+gelu;
// 3: f32 partial (no bias), output offset by split*M*N.
// ---------------------------------------------------------------------------
template<int MODE>
__global__ __launch_bounds__(256)
void gemm_bt_kernel(const __bf16* __restrict__ A, const __bf16* __restrict__ Bt,
                    const float* __restrict__ bias, void* __restrict__ Cout,
                    const int M, const int N, const int K, const int Kper)
{
  __shared__ __bf16 As[128 * 32];
  __shared__ __bf16 Bs[128 * 32];
  const int tid  = threadIdx.x;
  const int lane = tid & 63;
  const int wave = tid >> 6;
  const int col  = lane & 15;
  const int quad = lane >> 4;
  const int m0 = blockIdx.y * 128;
  const int n0 = blockIdx.x * 128;
  const int wm = (wave & 1) * 64;
  const int wn = (wave >> 1) * 64;
  const int s  = blockIdx.z;
  floatx4 acc[4][4] = {};

  const int srow = tid >> 2;
  const int scol = (tid & 3) * 8;
  const __bf16* Ag = A  + (size_t)s * Kper + (size_t)(m0 + srow) * K + scol;
  const __bf16* Bg = Bt + (size_t)s * Kper + (size_t)(n0 + srow) * K + scol;
  const size_t rowskip = (size_t)64 * K;

  for (int k0 = 0; k0 < Kper; k0 += 32) {
    glds16(Ag + k0,           As + tid * 8);
    glds16(Ag + k0 + rowskip, As + 2048 + tid * 8);
    glds16(Bg + k0,           Bs + tid * 8);
    glds16(Bg + k0 + rowskip, Bs + 2048 + tid * 8);
    __syncthreads();
    bf16x8 af[4], bf[4];
#pragma unroll
    for (int mi = 0; mi < 4; mi++)
      af[mi] = *(const bf16x8*)&As[(wm + mi * 16 + col) * 32 + quad * 8];
#pragma unroll
    for (int ni = 0; ni < 4; ni++)
      bf[ni] = *(const bf16x8*)&Bs[(wn + ni * 16 + col) * 32 + quad * 8];
#pragma unroll
    for (int mi = 0; mi < 4; mi++)
#pragma unroll
      for (int ni = 0; ni < 4; ni++)
        acc[mi][ni] = __builtin_amdgcn_mfma_f32_16x16x32_bf16(af[mi], bf[ni], acc[mi][ni], 0, 0, 0);
    __syncthreads();
  }

  float* Cp = (MODE == 3) ? ((float*)Cout + (size_t)s * M * N) : (float*)Cout;
#pragma unroll
  for (int ni = 0; ni < 4; ni++) {
    const int cc = n0 + wn + ni * 16 + col;
    const float bv = (MODE == 3) ? 0.f : bias[cc];
#pragma unroll
    for (int mi = 0; mi < 4; mi++) {
#pragma unroll
      for (int r = 0; r < 4; r++) {
        const int rr = m0 + wm + mi * 16 + quad * 4 + r;
        float v = acc[mi][ni][r] + bv;
        if constexpr (MODE == 2) v = gelu_tanh(v);
        if constexpr (MODE == 0 || MODE == 3)
          Cp[(size_t)rr * N + cc] = v;
        else
          ((__bf16*)Cout)[(size_t)rr * N + cc] = (__bf16)v;
      }
    }
  }
}

// ---------------------------------------------------------------------------
// Flash attention (MQA): grid (S/64, H, B), 256 threads (4 waves).
// ---------------------------------------------------------------------------
__global__ __launch_bounds__(256)
void flash_kernel(const __bf16* __restrict__ qkv, const __bf16* __restrict__ vT,
                  __bf16* __restrict__ ctx)
{
  const int qt = blockIdx.x, h = blockIdx.y, b = blockIdx.z;
  const int tid  = threadIdx.x;
  const int lane = tid & 63, wave = tid >> 6;
  const int col  = lane & 15, quad = lane >> 4;
  __shared__ __bf16 Qs[64 * 128];
  __shared__ __bf16 Ks[64 * 128];
  __shared__ __bf16 Vs[128 * 64];   // transposed: [d][key]
  __shared__ __bf16 Ps[4][16 * 64];

#pragma unroll
  for (int p = 0; p < 4; p++) {
    int c = tid + p * 256;
    glds16(qkv + (size_t)(b * 1024 + qt * 64 + (c >> 4)) * 2304 + h * 128 + (c & 15) * 8,
           Qs + c * 8);
  }

  float m_i[4], l_i[4];
  floatx4 o[8] = {};
#pragma unroll
  for (int r = 0; r < 4; r++) { m_i[r] = -1e30f; l_i[r] = 0.f; }

  for (int kt = 0; kt <= qt; kt++) {
    __syncthreads();
#pragma unroll
    for (int p = 0; p < 4; p++) {
      int c = tid + p * 256;
      glds16(qkv + (size_t)(b * 1024 + kt * 64 + (c >> 4)) * 2304 + 2048 + (c & 15) * 8,
             Ks + c * 8);
    }
#pragma unroll
    for (int p = 0; p < 4; p++) {
      int c = tid + p * 256;
      glds16(vT + (size_t)b * 131072 + (size_t)(c >> 3) * 1024 + kt * 64 + (c & 7) * 8,
             Vs + c * 8);
    }
    __syncthreads();

    floatx4 sc[4] = {};
#pragma unroll
    for (int kk = 0; kk < 4; kk++) {
      bf16x8 qa = *(const bf16x8*)&Qs[(wave * 16 + col) * 128 + kk * 32 + quad * 8];
#pragma unroll
      for (int ni = 0; ni < 4; ni++) {
        bf16x8 kb = *(const bf16x8*)&Ks[(ni * 16 + col) * 128 + kk * 32 + quad * 8];
        sc[ni] = __builtin_amdgcn_mfma_f32_16x16x32_bf16(qa, kb, sc[ni], 0, 0, 0);
      }
    }

    const bool diag = (kt == qt);
#pragma unroll
    for (int r = 0; r < 4; r++) {
      const int rowL = wave * 16 + quad * 4 + r;
      float mx = -1e30f;
#pragma unroll
      for (int ni = 0; ni < 4; ni++) {
        float s = sc[ni][r] * 0.08838834764831845f;
        if (diag && (ni * 16 + col) > rowL) s = -1e30f;
        sc[ni][r] = s;
        mx = fmaxf(mx, s);
      }
#pragma unroll
      for (int off = 1; off < 16; off <<= 1) mx = fmaxf(mx, __shfl_xor(mx, off));
      const float mnew = fmaxf(m_i[r], mx);
      const float alpha = __expf(m_i[r] - mnew);
      l_i[r] *= alpha;
      float rsum = 0.f;
#pragma unroll
      for (int ni = 0; ni < 4; ni++) {
        float p = __expf(sc[ni][r] - mnew);
        sc[ni][r] = p;
        rsum += p;
      }
#pragma unroll
      for (int off = 1; off < 16; off <<= 1) rsum += __shfl_xor(rsum, off);
      l_i[r] += rsum;
      m_i[r] = mnew;
#pragma unroll
      for (int nd = 0; nd < 8; nd++) o[nd][r] *= alpha;
    }

    __bf16* Pw = &Ps[wave][0];
#pragma unroll
    for (int r = 0; r < 4; r++)
#pragma unroll
      for (int ni = 0; ni < 4; ni++)
        Pw[(quad * 4 + r) * 64 + ni * 16 + col] = (__bf16)sc[ni][r];

#pragma unroll
    for (int kk = 0; kk < 2; kk++) {
      bf16x8 pa = *(const bf16x8*)&Pw[col * 64 + kk * 32 + quad * 8];
#pragma unroll
      for (int nd = 0; nd < 8; nd++) {
        bf16x8 vb = *(const bf16x8*)&Vs[(nd * 16 + col) * 64 + kk * 32 + quad * 8];
        o[nd] = __builtin_amdgcn_mfma_f32_16x16x32_bf16(pa, vb, o[nd], 0, 0, 0);
      }
    }
  }

#pragma unroll
  for (int r = 0; r < 4; r++) {
    const float inv = 1.f / l_i[r];
    const int row = qt * 64 + wave * 16 + quad * 4 + r;
    const size_t base = (size_t)(b * 1024 + row) * 2048 + h * 128;
#pragma unroll
    for (int nd = 0; nd < 8; nd++)
      ctx[base + nd * 16 + col] = (__bf16)(o[nd][r] * inv);
  }
}

// ---------------------------------------------------------------------------
// Orchestration
// ---------------------------------------------------------------------------
extern "C" void kernel_launch(void* const* d_in, const int* in_sizes, int n_in,
                              void* d_out, int out_size, void* d_ws, size_t ws_size,
                              hipStream_t stream)
{
  (void)in_sizes; (void)n_in; (void)out_size; (void)ws_size;
  const int*   ids = (const int*)d_in[0];
  const int*   pos = (const int*)d_in[1];
  const float* wte = (const float*)d_in[2];
  const float* wpe = (const float*)d_in[3];
  const float* caw = (const float*)d_in[4];
  const float* cab = (const float*)d_in[5];
  const float* cpw = (const float*)d_in[6];
  const float* cpb = (const float*)d_in[7];
  const float* l1w = (const float*)d_in[8];
  const float* l1b = (const float*)d_in[9];
  const float* l2w = (const float*)d_in[10];
  const float* l2b = (const float*)d_in[11];
  const float* fcw = (const float*)d_in[12];
  const float* fcb = (const float*)d_in[13];
  const float* mpw = (const float*)d_in[14];
  const float* mpb = (const float*)d_in[15];
  const float* lfw = (const float*)d_in[16];
  const float* lfb = (const float*)d_in[17];
  float* out = (float*)d_out;

  char* ws = (char*)d_ws;
  float*  resA  = (float*)(ws + 0);           // 16.8 MB
  float*  resB  = (float*)(ws + 16777216);    // 16.8 MB
  __bf16* xb    = (__bf16*)(ws + 33554432);   //  8.4 MB
  __bf16* qkvb  = (__bf16*)(ws + 41943040);   //  9.4 MB
  __bf16* ctxb  = (__bf16*)(ws + 51380224);   //  8.4 MB
  __bf16* vtb   = (__bf16*)(ws + 59768832);   //  0.5 MB
  __bf16* wqkvT = (__bf16*)(ws + 60293120);   //  9.4 MB (per-layer)
  __bf16* wprjT = (__bf16*)(ws + 69730304);   //  8.4 MB (per-layer)
  __bf16* wfcT  = (__bf16*)(ws + 78118912);   // 33.6 MB (per-layer)
  __bf16* wmpT  = (__bf16*)(ws + 111673344);  // 33.6 MB (per-layer)
  // time-shared arena: pq (2x2048x2304 f32 = 37.7MB) | pp (2x2048x2048 f32) |
  //                    mlp1b (2048x8192 bf16 = 33.6MB) — disjoint live ranges
  char*   arena = ws + 145227776;             // 37.75 MB
  float*  pq    = (float*)arena;
  float*  pp    = (float*)arena;
  __bf16* mlp1b = (__bf16*)arena;
  float*  pm    = (float*)(ws + 182976512);   // 4x2048x2048 f32 = 67.1 MB
  // total: 250.1 MB (round-1 proved >= 280.6 MB available)

  const size_t MN  = (size_t)2048 * 2048;   // per-split partial stride (proj/mp)
  const size_t MNq = (size_t)2048 * 2304;   // qkv partial stride

  embed_kernel<<<2048, 256, 0, stream>>>(ids, pos, wte, wpe, resA);

  for (int l = 0; l < 2; l++) {
    // --- ln1: res = h (+ residual); also reduces prev layer's mp partials ---
    if (l == 0)
      ln_red_kernel<<<2048, 256, 0, stream>>>(
          resA, nullptr, nullptr, nullptr, nullptr, nullptr,
          nullptr, xb, nullptr, l1w, l1b);
    else
      ln_red_kernel<<<2048, 256, 0, stream>>>(
          pm, pm + MN, pm + 2 * MN, pm + 3 * MN, mpb, resB,
          resA, xb, nullptr, l1w + 2048, l1b + 2048);

    // --- qkv = x @ c_attn_w + b  (split-K x2) ---
    wcvt_kernel<<<dim3(72, 64), 256, 0, stream>>>(caw + (size_t)l * 2048 * 2304,
                                                  wqkvT, 2048, 2304);
    gemm_bt_kernel<3><<<dim3(18, 16, 2), 256, 0, stream>>>(
        xb, wqkvT, nullptr, pq, 2048, 2304, 2048, 1024);
    bias_red_bf16_kernel<<<4608, 256, 0, stream>>>(pq, pq + MNq, cab + l * 2304, qkvb);

    // --- attention ---
    vtr_kernel<<<dim3(4, 32, 2), 256, 0, stream>>>(qkvb, vtb);
    flash_kernel<<<dim3(16, 16, 2), 256, 0, stream>>>(qkvb, vtb, ctxb);

    // --- attn_out = ctx @ c_proj_w + b (split-K x2), fused into ln2 ---
    wcvt_kernel<<<dim3(64, 64), 256, 0, stream>>>(cpw + (size_t)l * 2048 * 2048,
                                                  wprjT, 2048, 2048);
    gemm_bt_kernel<3><<<dim3(16, 16, 2), 256, 0, stream>>>(
        ctxb, wprjT, nullptr, pp, 2048, 2048, 2048, 1024);
    ln_red_kernel<<<2048, 256, 0, stream>>>(
        pp, pp + MN, nullptr, nullptr, cpb + l * 2048, resA,
        resB, xb, nullptr, l2w + l * 2048, l2b + l * 2048);

    // --- mlp1 = gelu(x2 @ fc_w + b) ---
    wcvt_kernel<<<dim3(256, 64), 256, 0, stream>>>(fcw + (size_t)l * 2048 * 8192,
                                                   wfcT, 2048, 8192);
    gemm_bt_kernel<2><<<dim3(64, 16, 1), 256, 0, stream>>>(
        xb, wfcT, fcb + l * 8192, mlp1b, 2048, 8192, 2048, 2048);

    // --- mlp = mlp1 @ mp_w + b (split-K x4), reduced in next LN ---
    wcvt_kernel<<<dim3(64, 256), 256, 0, stream>>>(mpw + (size_t)l * 8192 * 2048,
                                                   wmpT, 8192, 2048);
    gemm_bt_kernel<3><<<dim3(16, 16, 4), 256, 0, stream>>>(
        mlp1b, wmpT, nullptr, pm, 2048, 2048, 8192, 2048);
  }

  // final: ln(h + residual) = ln(mp_out + resB)
  ln_red_kernel<<<2048, 256, 0, stream>>>(
      pm, pm + MN, pm + 2 * MN, pm + 3 * MN, mpb + 2048, resB,
      nullptr, nullptr, out, lfw, lfb);
}